// Round 4
// baseline (3933.782 us; speedup 1.0000x reference)
//
#include <hip/hip_runtime.h>
#include <cstdint>
#include <cstddef>

typedef __attribute__((ext_vector_type(8))) short s16x8;
typedef __attribute__((ext_vector_type(4))) float f32x4;
typedef __attribute__((ext_vector_type(4))) unsigned int u32x4;

#define DEV static __device__ __forceinline__

DEV unsigned short f2bf(float f){
  unsigned u = __builtin_bit_cast(unsigned, f);
  unsigned r = u + 0x7FFFu + ((u >> 16) & 1u);   // RNE
  return (unsigned short)(r >> 16);
}
DEV float bf2f(unsigned short s){
  unsigned u = ((unsigned)s) << 16;
  return __builtin_bit_cast(float, u);
}
DEV float sigf(float v){ return 1.0f / (1.0f + __expf(-v)); }
DEV float tanh_f(float v){ return 1.0f - 2.0f / (__expf(2.0f*v) + 1.0f); }

#define NT 32
#define NF 64
#define NHID 256
#define MR 112   // rows (nodes) per LSTM workgroup
#define RT 7     // 16-row tiles per workgroup

// ---------------- weight packing ----------------
// LSTM combined weights W[g][k], k<256 -> w_hh[g][k], k>=256 -> w_ih[g][k-256].
// Packed in MFMA B-frag order: frag idx = (ct*10 + kc)*64 + lane, 8 bf16 each.
// B[k][col]: col = ct*16 + (lane&15), k = kc*32 + (lane>>4)*8 + j.
__global__ void pack_lstm_kernel(const float* __restrict__ w_ih,
                                 const float* __restrict__ w_hh,
                                 unsigned short* __restrict__ wp){
  int idx = blockIdx.x*256 + threadIdx.x;          // 0..40959
  if (idx >= 64*10*64) return;
  int lane = idx & 63;
  int kc = (idx >> 6) % 10;
  int ct = idx / 640;
  int col = ct*16 + (lane & 15);
  int kb = kc*32 + (lane >> 4)*8;
#pragma unroll
  for (int j = 0; j < 8; ++j){
    int k = kb + j;
    float v = (k < 256) ? w_hh[(size_t)col*256 + k] : w_ih[(size_t)col*64 + (k-256)];
    wp[(size_t)idx*8 + j] = f2bf(v);
  }
}

// pack w (K=256, NOUT cols) row-major w[k*nout+col] into B-frag order, KC=8.
__global__ void pack_gemm_kernel(const float* __restrict__ wsrc,
                                 unsigned short* __restrict__ bp,
                                 int nout, int nct){
  int idx = blockIdx.x*256 + threadIdx.x;
  if (idx >= nct*8*64) return;
  int lane = idx & 63;
  int kc = (idx >> 6) & 7;
  int ct = idx >> 9;
  int col = ct*16 + (lane & 15);
  int kb = kc*32 + (lane >> 4)*8;
#pragma unroll
  for (int j = 0; j < 8; ++j)
    bp[(size_t)idx*8 + j] = f2bf(wsrc[(size_t)(kb + j)*nout + col]);
}

__global__ void bias_kernel(const float* __restrict__ bi, const float* __restrict__ bh,
                            float* __restrict__ bias){
  int i = blockIdx.x*256 + threadIdx.x;
  if (i < 1024) bias[i] = bi[i] + bh[i];
}

// ---------------- graph prep (CSR by dst) ----------------
__global__ void init_nodes_kernel(int* cnt, int* fill, int nn){
  int i = blockIdx.x*256 + threadIdx.x;
  if (i < nn){ cnt[i] = 0; fill[i] = 0; }
}
__global__ void count_kernel(const int* __restrict__ dst, int* cnt, int ne){
  int e = blockIdx.x*256 + threadIdx.x;
  if (e < ne) atomicAdd(&cnt[dst[e]], 1);
}
__global__ void dinv_kernel(const int* __restrict__ cnt, float* dinv, int nn){
  int i = blockIdx.x*256 + threadIdx.x;
  if (i < nn) dinv[i] = rsqrtf((float)(cnt[i] + 1));   // +1 self loop
}
__global__ void scan_kernel(const int* __restrict__ cnt, int* __restrict__ rp, int nn){
  __shared__ int sums[1024];
  int tid = threadIdx.x;
  int chunk = (nn + 1023) >> 10;
  int beg = tid * chunk, end = beg + chunk; if (end > nn) end = nn; if (beg > nn) beg = nn;
  int s = 0;
  for (int i = beg; i < end; ++i) s += cnt[i];
  sums[tid] = s; __syncthreads();
  for (int off = 1; off < 1024; off <<= 1){
    int add = (tid >= off) ? sums[tid - off] : 0;
    __syncthreads();
    sums[tid] += add;
    __syncthreads();
  }
  int run = (tid > 0) ? sums[tid - 1] : 0;
  for (int i = beg; i < end; ++i){ rp[i] = run; run += cnt[i]; }
  if (tid == 0) rp[nn] = sums[1023];
}
__global__ void fill_kernel(const int* __restrict__ src, const int* __restrict__ dst,
                            const int* __restrict__ rp, int* fill, int* ci, int ne){
  int e = blockIdx.x*256 + threadIdx.x;
  if (e < ne){
    int d = dst[e];
    int p = atomicAdd(&fill[d], 1);
    ci[rp[d] + p] = src[e];
  }
}

// ---------------- fused LSTM ----------------
DEV void load_x16p(const float* p, unsigned* xs32){
#pragma unroll
  for (int i = 0; i < 4; ++i){
    f32x4 v = ((const f32x4*)p)[i];
    xs32[i*2]   = (unsigned)f2bf(v[0]) | ((unsigned)f2bf(v[1]) << 16);
    xs32[i*2+1] = (unsigned)f2bf(v[2]) | ((unsigned)f2bf(v[3]) << 16);
  }
}

__global__ __launch_bounds__(512, 2)
void lstm_kernel(const float* __restrict__ x, const s16x8* __restrict__ wp,
                 const float* __restrict__ bias, unsigned short* __restrict__ feats0,
                 int nn){
  extern __shared__ char smem[];
  // h double-buffered: [2][MR][264] bf16 (264 pad -> 528B row = 132 dwords == 4 mod 32:
  // consecutive rows start 4 banks apart -> 16-lane column reads spread all 32 banks, 2-way max)
  unsigned short (*h_lds)[MR][264] = (unsigned short (*)[MR][264])smem;
  // x tile: [MR][72] bf16 (144B row = 36 dwords == 4 mod 32, same spread)
  unsigned short (*x_lds)[72] = (unsigned short (*)[72])(smem + (size_t)2*MR*264*2);

  const int tid = threadIdx.x;
  const int w = tid >> 6;
  const int l = tid & 63;
  const int lrow = l & 15;
  const int lhi = l >> 4;
  const int base = blockIdx.x * MR;

  // per-wave bias values (gate g, pass p -> unit tile p*8+w)
  float bv[2][4];
#pragma unroll
  for (int p = 0; p < 2; ++p)
#pragma unroll
    for (int g = 0; g < 4; ++g)
      bv[p][g] = bias[g*256 + (p*8 + w)*16 + lrow];

  float c[2][RT][4];
#pragma unroll
  for (int p = 0; p < 2; ++p)
#pragma unroll
    for (int r = 0; r < RT; ++r)
#pragma unroll
      for (int q = 0; q < 4; ++q) c[p][r][q] = 0.0f;

  // zero h buffer 0
  {
    unsigned* hz = (unsigned*)smem;
    for (int i = tid; i < MR*264/2; i += 512) hz[i] = 0u;
  }

  // x staging assignment: 448 active threads, 4 chunks of 16 floats per row
  const bool xact = (tid < 448);
  const int xr = tid >> 2, xc = tid & 3;
  long xnode = base + xr; if (xnode >= nn) xnode = nn - 1;
  const float* xb = x + (size_t)xnode * NT * NF + xc * 16;

  unsigned xs32[8];
  if (xact){
    load_x16p(xb, xs32);                       // x_0
    u32x4 a = {xs32[0], xs32[1], xs32[2], xs32[3]};
    u32x4 b = {xs32[4], xs32[5], xs32[6], xs32[7]};
    *(u32x4*)&x_lds[xr][xc*16]     = a;
    *(u32x4*)&x_lds[xr][xc*16 + 8] = b;
  }
  __syncthreads();

  for (int t = 0; t < NT; ++t){
    const int tb = t & 1;
    if (xact && (t + 1 < NT)) load_x16p(xb + (size_t)(t+1)*NF, xs32);  // prefetch x_{t+1}

#pragma unroll
    for (int p = 0; p < 2; ++p){
      const int ut = p*8 + w;           // unit tile (16 hidden units)
      f32x4 acc[RT][4];
#pragma unroll
      for (int r = 0; r < RT; ++r)
#pragma unroll
        for (int g = 0; g < 4; ++g)
          acc[r][g] = (f32x4){bv[p][g], bv[p][g], bv[p][g], bv[p][g]};

#pragma unroll
      for (int kc = 0; kc < 10; ++kc){
        s16x8 bfr[4];
#pragma unroll
        for (int g = 0; g < 4; ++g){
          int ct = g*16 + ut;
          bfr[g] = wp[(size_t)(ct*10 + kc)*64 + l];
        }
#pragma unroll
        for (int r = 0; r < RT; ++r){
          s16x8 afr;
          if (kc < 8)
            afr = *(const s16x8*)&h_lds[tb][r*16 + lrow][kc*32 + lhi*8];
          else
            afr = *(const s16x8*)&x_lds[r*16 + lrow][(kc-8)*32 + lhi*8];
#pragma unroll
          for (int g = 0; g < 4; ++g)
            acc[r][g] = __builtin_amdgcn_mfma_f32_16x16x32_bf16(afr, bfr[g], acc[r][g], 0, 0, 0);
        }
      }
      // elementwise: c' = sig(f)c + sig(i)tanh(g); h = sig(o)tanh(c')
#pragma unroll
      for (int r = 0; r < RT; ++r){
#pragma unroll
        for (int q = 0; q < 4; ++q){
          float iv = acc[r][0][q];
          float fv = acc[r][1][q];
          float gv = acc[r][2][q];
          float ov = acc[r][3][q];
          float cv = c[p][r][q];
          cv = sigf(fv)*cv + sigf(iv)*tanh_f(gv);
          c[p][r][q] = cv;
          float hv = sigf(ov)*tanh_f(cv);
          h_lds[tb^1][r*16 + lhi*4 + q][ut*16 + lrow] = f2bf(hv);
        }
      }
    }
    __syncthreads();           // all reads of x_lds / h_lds[tb] done
    if (xact && (t + 1 < NT)){
      u32x4 a = {xs32[0], xs32[1], xs32[2], xs32[3]};
      u32x4 b = {xs32[4], xs32[5], xs32[6], xs32[7]};
      *(u32x4*)&x_lds[xr][xc*16]     = a;
      *(u32x4*)&x_lds[xr][xc*16 + 8] = b;
    }
    __syncthreads();
  }

  // final h (t=31 wrote buffer 0): coalesced store to feats0
#pragma unroll
  for (int i = 0; i < 7; ++i){
    int ch = i*512 + tid;              // 3584 = 112 rows * 32 chunks
    int row = ch >> 5, cc = ch & 31;
    long node = base + row;
    if (node < nn){
      s16x8 v = *(const s16x8*)&h_lds[0][row][cc*8];
      *(s16x8*)&feats0[(size_t)node*256 + cc*8] = v;
    }
  }
}

// ---------------- small GEMM: [nn,256] @ packed B -> [nn,NOUT] bf16 ----------------
template<int CTPW, int NOUT>
__global__ __launch_bounds__(256)
void gemm_kernel(const unsigned short* __restrict__ A, const s16x8* __restrict__ Bp,
                 unsigned short* __restrict__ Cout, int nn){
  __shared__ __align__(16) unsigned short a_lds[64][264];
  const int tid = threadIdx.x, w = tid >> 6, l = tid & 63, lrow = l & 15, lhi = l >> 4;
  const long m0 = (long)blockIdx.x * 64;
#pragma unroll
  for (int i = 0; i < 8; ++i){
    int ch = i*256 + tid;
    int row = ch >> 5, cc = ch & 31;
    long node = m0 + row; if (node >= nn) node = nn - 1;
    s16x8 v = *(const s16x8*)&A[(size_t)node*256 + cc*8];
    *(s16x8*)&a_lds[row][cc*8] = v;
  }
  __syncthreads();
  f32x4 acc[4][CTPW];
#pragma unroll
  for (int r = 0; r < 4; ++r)
#pragma unroll
    for (int j = 0; j < CTPW; ++j) acc[r][j] = (f32x4){0.f,0.f,0.f,0.f};
#pragma unroll
  for (int kc = 0; kc < 8; ++kc){
    s16x8 bfr[CTPW];
#pragma unroll
    for (int j = 0; j < CTPW; ++j)
      bfr[j] = Bp[(size_t)((w*CTPW + j)*8 + kc)*64 + l];
#pragma unroll
    for (int r = 0; r < 4; ++r){
      s16x8 afr = *(const s16x8*)&a_lds[r*16 + lrow][kc*32 + lhi*8];
#pragma unroll
      for (int j = 0; j < CTPW; ++j)
        acc[r][j] = __builtin_amdgcn_mfma_f32_16x16x32_bf16(afr, bfr[j], acc[r][j], 0, 0, 0);
    }
  }
#pragma unroll
  for (int r = 0; r < 4; ++r)
#pragma unroll
    for (int j = 0; j < CTPW; ++j){
      int col = (w*CTPW + j)*16 + lrow;
#pragma unroll
      for (int q = 0; q < 4; ++q){
        long node = m0 + r*16 + lhi*4 + q;
        if (node < nn) Cout[(size_t)node*NOUT + col] = f2bf(acc[r][j][q]);
      }
    }
}

// ---------------- GCN gather: out[d] = relu(sum_e norm*tmp[src] + self + b) ----------------
template<int D>
__global__ __launch_bounds__(256)
void gather_kernel(const unsigned short* __restrict__ tmp, const int* __restrict__ rp,
                   const int* __restrict__ ci, const float* __restrict__ dinv,
                   const float* __restrict__ bvec, unsigned short* __restrict__ outf,
                   int nn){
  const int l = threadIdx.x & 63;
  const int d = blockIdx.x*4 + (threadIdx.x >> 6);
  if (d >= nn) return;
  constexpr int C = D / 64;
  float dv = dinv[d];
  float acc[C];
  // self loop: norm = dinv[d]^2
  if constexpr (D == 256){
    uint2 u = *((const uint2*)(tmp + (size_t)d*256) + l);
    float w0 = dv*dv;
    acc[0] = w0*bf2f((unsigned short)(u.x & 0xffff));
    acc[1] = w0*bf2f((unsigned short)(u.x >> 16));
    acc[2] = w0*bf2f((unsigned short)(u.y & 0xffff));
    acc[3] = w0*bf2f((unsigned short)(u.y >> 16));
  } else {
    unsigned u = *((const unsigned*)(tmp + (size_t)d*128) + l);
    float w0 = dv*dv;
    acc[0] = w0*bf2f((unsigned short)(u & 0xffff));
    acc[1] = w0*bf2f((unsigned short)(u >> 16));
  }
  int e0 = rp[d], e1 = rp[d+1];
  for (int e = e0; e < e1; ++e){
    int s = ci[e];
    float wgt = dv * dinv[s];
    if constexpr (D == 256){
      uint2 u = *((const uint2*)(tmp + (size_t)s*256) + l);
      acc[0] += wgt*bf2f((unsigned short)(u.x & 0xffff));
      acc[1] += wgt*bf2f((unsigned short)(u.x >> 16));
      acc[2] += wgt*bf2f((unsigned short)(u.y & 0xffff));
      acc[3] += wgt*bf2f((unsigned short)(u.y >> 16));
    } else {
      unsigned u = *((const unsigned*)(tmp + (size_t)s*128) + l);
      acc[0] += wgt*bf2f((unsigned short)(u & 0xffff));
      acc[1] += wgt*bf2f((unsigned short)(u >> 16));
    }
  }
  if constexpr (D == 256){
    float o0 = fmaxf(acc[0] + bvec[l*4+0], 0.f);
    float o1 = fmaxf(acc[1] + bvec[l*4+1], 0.f);
    float o2 = fmaxf(acc[2] + bvec[l*4+2], 0.f);
    float o3 = fmaxf(acc[3] + bvec[l*4+3], 0.f);
    uint2 o;
    o.x = (unsigned)f2bf(o0) | ((unsigned)f2bf(o1) << 16);
    o.y = (unsigned)f2bf(o2) | ((unsigned)f2bf(o3) << 16);
    *((uint2*)(outf + (size_t)d*256) + l) = o;
  } else {
    float o0 = fmaxf(acc[0] + bvec[l*2+0], 0.f);
    float o1 = fmaxf(acc[1] + bvec[l*2+1], 0.f);
    *((unsigned*)(outf + (size_t)d*128) + l) = (unsigned)f2bf(o0) | ((unsigned)f2bf(o1) << 16);
  }
}

// ---------------- head: logits + softmax ----------------
__global__ __launch_bounds__(256)
void head_kernel(const unsigned short* __restrict__ feats2, const float* __restrict__ wc,
                 const float* __restrict__ bc, float* __restrict__ out, int nn){
  int n = blockIdx.x*256 + threadIdx.x;
  if (n >= nn) return;
  const uint2* row = (const uint2*)(feats2 + (size_t)n*128);
  float d0 = bc[0], d1 = bc[1];
#pragma unroll
  for (int b = 0; b < 32; ++b){
    uint2 u = row[b];
    float f0 = bf2f((unsigned short)(u.x & 0xffff));
    float f1 = bf2f((unsigned short)(u.x >> 16));
    float f2 = bf2f((unsigned short)(u.y & 0xffff));
    float f3 = bf2f((unsigned short)(u.y >> 16));
    int k = b*4;
    d0 += f0*wc[k*2+0] + f1*wc[(k+1)*2+0] + f2*wc[(k+2)*2+0] + f3*wc[(k+3)*2+0];
    d1 += f0*wc[k*2+1] + f1*wc[(k+1)*2+1] + f2*wc[(k+2)*2+1] + f3*wc[(k+3)*2+1];
  }
  float m = fmaxf(d0, d1);
  float e0 = __expf(d0 - m), e1 = __expf(d1 - m);
  float inv = 1.0f / (e0 + e1);
  ((float2*)out)[n] = make_float2(e0*inv, e1*inv);
}

// ---------------- launch ----------------
extern "C" void kernel_launch(void* const* d_in, const int* in_sizes, int n_in,
                              void* d_out, int out_size, void* d_ws, size_t ws_size,
                              hipStream_t stream){
  const float* x     = (const float*)d_in[0];
  const int*   ei    = (const int*)d_in[1];
  const float* w_ih  = (const float*)d_in[2];
  const float* w_hh  = (const float*)d_in[3];
  const float* b_ih  = (const float*)d_in[4];
  const float* b_hh  = (const float*)d_in[5];
  const float* w1    = (const float*)d_in[6];
  const float* b1    = (const float*)d_in[7];
  const float* w2    = (const float*)d_in[8];
  const float* b2    = (const float*)d_in[9];
  const float* wc    = (const float*)d_in[10];
  const float* bc    = (const float*)d_in[11];
  float* out = (float*)d_out;

  const int nn = in_sizes[0] / (NT*NF);   // 50000
  const int ne = in_sizes[1] / 2;         // 1600000
  const int* src = ei;
  const int* dst = ei + ne;

  char* wsp = (char*)d_ws;
  size_t off = 0;
  auto alloc = [&](size_t bytes) -> void* {
    void* p = wsp + off;
    off += (bytes + 255) & ~(size_t)255;
    return p;
  };
  unsigned short* wp     = (unsigned short*)alloc((size_t)64*10*64*8*2);
  float* bias            = (float*)alloc(1024*4);
  unsigned short* w1p    = (unsigned short*)alloc((size_t)16*8*64*8*2);
  unsigned short* w2p    = (unsigned short*)alloc((size_t)8*8*64*8*2);
  int* cnt               = (int*)alloc((size_t)nn*4);
  float* dinv            = (float*)alloc((size_t)nn*4);
  int* rp                = (int*)alloc(((size_t)nn+1)*4);
  int* fillc             = (int*)alloc((size_t)nn*4);
  int* ci                = (int*)alloc((size_t)ne*4);
  // Aliased feature slots (dataflow-safe; halves workspace footprint):
  //   slotA: feats0 (lstm out) -> dead after gemm1 -> feats1 lives here
  //   slotB: tmp1 (gemm1 out)  -> dead after gather1 -> tmp2 + feats2 live here
  unsigned short* slotA  = (unsigned short*)alloc((size_t)nn*256*2);
  unsigned short* slotB  = (unsigned short*)alloc((size_t)nn*256*2);
  unsigned short* feats0 = slotA;
  unsigned short* tmp1   = slotB;
  unsigned short* feats1 = slotA;
  unsigned short* tmp2   = slotB;                          // first nn*128 of slotB
  unsigned short* feats2 = slotB + (size_t)nn*128;         // second half of slotB
  (void)ws_size; (void)n_in; (void)out_size;

  const int nb = (nn + 255)/256;
  const int eb = (ne + 255)/256;

  hipLaunchKernelGGL(pack_lstm_kernel, dim3(160), dim3(256), 0, stream, w_ih, w_hh, wp);
  hipLaunchKernelGGL(pack_gemm_kernel, dim3(32), dim3(256), 0, stream, w1, w1p, 256, 16);
  hipLaunchKernelGGL(pack_gemm_kernel, dim3(16), dim3(256), 0, stream, w2, w2p, 128, 8);
  hipLaunchKernelGGL(bias_kernel, dim3(4), dim3(256), 0, stream, b_ih, b_hh, bias);
  hipLaunchKernelGGL(init_nodes_kernel, dim3(nb), dim3(256), 0, stream, cnt, fillc, nn);
  hipLaunchKernelGGL(count_kernel, dim3(eb), dim3(256), 0, stream, dst, cnt, ne);
  hipLaunchKernelGGL(dinv_kernel, dim3(nb), dim3(256), 0, stream, cnt, dinv, nn);
  hipLaunchKernelGGL(scan_kernel, dim3(1), dim3(1024), 0, stream, cnt, rp, nn);
  hipLaunchKernelGGL(fill_kernel, dim3(eb), dim3(256), 0, stream, src, dst, rp, fillc, ci, ne);

  const int lwg = (nn + MR - 1)/MR;  // 447
  const size_t lstm_lds = (size_t)2*MR*264*2 + (size_t)MR*72*2;  // 134,400 B
  hipLaunchKernelGGL(lstm_kernel, dim3(lwg), dim3(512), lstm_lds, stream,
                     x, (const s16x8*)wp, bias, feats0, nn);

  const int gwg = (nn + 63)/64;      // 782
  const int awg = (nn + 3)/4;        // 12500
  hipLaunchKernelGGL((gemm_kernel<4,256>), dim3(gwg), dim3(256), 0, stream,
                     feats0, (const s16x8*)w1p, tmp1, nn);
  hipLaunchKernelGGL((gather_kernel<256>), dim3(awg), dim3(256), 0, stream,
                     tmp1, rp, ci, dinv, b1, feats1, nn);
  hipLaunchKernelGGL((gemm_kernel<2,128>), dim3(gwg), dim3(256), 0, stream,
                     feats1, (const s16x8*)w2p, tmp2, nn);
  hipLaunchKernelGGL((gather_kernel<128>), dim3(awg), dim3(256), 0, stream,
                     tmp2, rp, ci, dinv, b2, feats2, nn);
  hipLaunchKernelGGL(head_kernel, dim3(nb), dim3(256), 0, stream, feats2, wc, bc, out, nn);
}